// Round 11
// baseline (177.152 us; speedup 1.0000x reference)
//
#include <hip/hip_runtime.h>
#include <cstdint>
#include <cstddef>

#define BATCH 8192
#define DIN   1025
#define HID   1024
#define NACT  1026
#define NHEAD 513
#define KSEL  32
#define KP0   1088   /* DIN padded to multiple of 64 */
#define LGN   1024   /* logits cols 0..1023 via GEMM; 1024/1025 computed in sample */

typedef unsigned short u16;
typedef short bf16x8 __attribute__((ext_vector_type(8)));
typedef float f32x4 __attribute__((ext_vector_type(4)));

__device__ __forceinline__ u16 f2bf(float f) {
  unsigned u = __float_as_uint(f);
  u += 0x7fff + ((u >> 16) & 1);   // round-to-nearest-even
  return (u16)(u >> 16);
}
__device__ __forceinline__ float bf2f(u16 h) {
  return __uint_as_float((unsigned)h << 16);
}

__device__ __forceinline__ void async_cp16(const u16* g, u16* l) {
  __builtin_amdgcn_global_load_lds((const __attribute__((address_space(1))) void*)g,
                                   (__attribute__((address_space(3))) void*)l,
                                   16, 0, 0);
}

// ---------------- conversion kernel (512 thr, grid 4352) ----------------
// blocks: state cvt one pass (4352*512*4 = BATCH*KP0); blocks 0..3136 also do one
// 32x32 weight-transpose tile each (W0t 1088, W1t 1024, W2t 1024, W2c 1).
__global__ __launch_bounds__(512) void k_cvt(const float* __restrict__ state,
    const float* __restrict__ W0, const float* __restrict__ W1,
    const float* __restrict__ W2,
    u16* __restrict__ As, u16* __restrict__ W0t, u16* __restrict__ W1t,
    u16* __restrict__ W2t, u16* __restrict__ W2c) {
  const int tid = threadIdx.x;
  const int b = blockIdx.x;
  // state f32 [B][DIN] -> bf16 [B][KP0], 4 elems/thread
  {
    int i = b * 512 + tid;
    const int QPR = KP0 / 4;   // 272
    int r = i / QPR, c4 = (i - r * QPR) * 4;
    const float* src = state + (size_t)r * DIN + c4;
    ushort4 o;
    if (c4 + 3 < DIN) {
      o.x = f2bf(src[0]); o.y = f2bf(src[1]); o.z = f2bf(src[2]); o.w = f2bf(src[3]);
    } else {
      o.x = (c4 + 0 < DIN) ? f2bf(src[0]) : 0;
      o.y = (c4 + 1 < DIN) ? f2bf(src[1]) : 0;
      o.z = (c4 + 2 < DIN) ? f2bf(src[2]) : 0;
      o.w = (c4 + 3 < DIN) ? f2bf(src[3]) : 0;
    }
    *(ushort4*)(As + (size_t)r * KP0 + c4) = o;
  }
  if (b >= 3137) return;
  if (b == 3136) {   // W2 cols 1024,1025 -> W2c[2][1024]
    for (int e = tid; e < 2048; e += 512) {
      int j = e >> 10, k = e & 1023;
      W2c[e] = f2bf(W2[(size_t)k * NACT + 1024 + j]);
    }
    return;
  }
  const float* W; u16* Wt; int K, ldW, Kp, tt = b;
  if (tt < 1088)      { W = W0; Wt = W0t; K = DIN; ldW = HID;  Kp = KP0; }
  else if (tt < 2112) { tt -= 1088; W = W1; Wt = W1t; K = HID; ldW = HID;  Kp = HID; }
  else                { tt -= 2112; W = W2; Wt = W2t; K = HID; ldW = NACT; Kp = HID; }
  int n0 = (tt & 31) * 32, k0 = (tt >> 5) * 32;
  __shared__ float tile[32][33];
  const int tx = tid & 31, ty = tid >> 5;   // ty 0..15
#pragma unroll
  for (int i = 0; i < 32; i += 16) {
    int k = k0 + ty + i;
    tile[ty + i][tx] = (k < K) ? W[(size_t)k * ldW + n0 + tx] : 0.f;
  }
  __syncthreads();
#pragma unroll
  for (int i = 0; i < 32; i += 16)
    Wt[(size_t)(n0 + ty + i) * Kp + k0 + tx] = f2bf(tile[tx][ty + i]);
}

// ---- GEMM: block tile 128x128, 256 thr = 4 waves (2M x 2N, 64x64 each) ---------
// C[M][ldc] = A[M][K]*Bt[N][K]^T (+bias, relu). BK=64. Banked optimum lineage:
// r3 179 -> r10 175.8 (setprio + split A/B staging issue). 2 blocks/CU (grid
// 512, 64KB LDS dbuf): co-resident block hides each barrier drain (m114).
// r11 delta (loop-body only, revertible): hoist ALL 32 ds_reads (kk0+kk1
// fragments) to iter start so kk1's LDS latency hides under the kk0 MFMA
// cluster (compiler emits fine-grained lgkmcnt). +32 VGPR (~124), fine at the
// 256/wave cap of 2 waves/SIMD. Ledger unchanged: A(it+1) issued then
// vmcnt(4) drains the oldest 8 = tile it (FIFO); B(it+1) under kk0 shadow;
// end-of-iter lgkmcnt(0)+barrier protects buf reuse.
// Bank swizzle (r4-PMC-verified 0-conflict): chunk c -> row c>>3, slot c&7,
// source kchunk g = slot^(row&7); read slot (kk*4+lq)^(lr&7).
template<bool RELU, int K>
__global__ __launch_bounds__(256, 2)
void gemm_bt(const u16* __restrict__ A, const u16* __restrict__ Bt,
             const float* __restrict__ bias, u16* __restrict__ Cout, int ldc)
{
  __shared__ __align__(16) u16 lds[32768];   // 2 bufs x (A 8192 + B 8192 u16) = 64 KB

  const int d     = blockIdx.x;
  const int m8    = d & 7;
  const int ntile = (d >> 3) & 7;
  const int mtile = ((d >> 6) << 3) | m8;
  const size_t bm = (size_t)mtile * 128;
  const size_t bn = (size_t)ntile * 128;

  const int tid  = threadIdx.x;
  const int wave = tid >> 6;
  const int lane = tid & 63;
  const int waveM = wave >> 1, waveN = wave & 1;   // 2 x 2 waves, 64x64 each
  const int lr = lane & 15, lq = lane >> 4;

  // staging (per thread, 8 chunks of 16B): chunk c (0..1023 per matrix) ->
  // row = c>>3, slot = c&7, source kchunk g = slot ^ (row&7). Thread t handles
  // c = t + 256k, k=0..3: row = (t>>3)+32k (row&7 const), slot = t&7 const ->
  // g_ = (t&7) ^ ((t>>3)&7) constant per thread. LDS dest is linear (c*16B),
  // satisfying global_load_lds's wave-uniform-base+lane*16 rule.
  const int row0 = tid >> 3;                       // 0..31
  const int g_   = (tid & 7) ^ ((tid >> 3) & 7);
  const u16* gA0 = A  + (bm + row0)      * (size_t)K + g_ * 8;
  const u16* gA1 = A  + (bm + row0 + 32) * (size_t)K + g_ * 8;
  const u16* gA2 = A  + (bm + row0 + 64) * (size_t)K + g_ * 8;
  const u16* gA3 = A  + (bm + row0 + 96) * (size_t)K + g_ * 8;
  const u16* gB0 = Bt + (bn + row0)      * (size_t)K + g_ * 8;
  const u16* gB1 = Bt + (bn + row0 + 32) * (size_t)K + g_ * 8;
  const u16* gB2 = Bt + (bn + row0 + 64) * (size_t)K + g_ * 8;
  const u16* gB3 = Bt + (bn + row0 + 96) * (size_t)K + g_ * 8;
  u16* lA = lds + wave * 512;          // + 2048*k per chunk; +buf*16384
  u16* lB = lds + 8192 + wave * 512;

  f32x4 acc[4][4] = {};

  // fragment read: row = base16 + lr so row&7 = lr&7 = xr. For k-half kk the
  // wanted kchunk g* = kk*4+lq sits at slot (kk*4+lq)^xr.
  const int xr  = lane & 7;
  const int sk0 = ((0 | lq) ^ xr) * 8;   // u16 offset within row, kk=0
  const int sk1 = ((4 | lq) ^ xr) * 8;   // kk=1
  const u16* pa = lds + (waveM * 64 + lr) * 64;
  const u16* pb = lds + 8192 + (waveN * 64 + lr) * 64;

  auto issueA = [&](int k0, int buf) {
    const int o = buf * 16384;
    async_cp16(gA0 + k0, lA + o);
    async_cp16(gA1 + k0, lA + o + 2048);
    async_cp16(gA2 + k0, lA + o + 4096);
    async_cp16(gA3 + k0, lA + o + 6144);
  };
  auto issueB = [&](int k0, int buf) {
    const int o = buf * 16384;
    async_cp16(gB0 + k0, lB + o);
    async_cp16(gB1 + k0, lB + o + 2048);
    async_cp16(gB2 + k0, lB + o + 4096);
    async_cp16(gB3 + k0, lB + o + 6144);
  };

  const int NIT = K / 64;
  issueA(0, 0);
  issueB(0, 0);
#pragma unroll 2
  for (int it = 0; it < NIT; ++it) {
    const int buf = it & 1;
    // Ledger: at iter entry in-flight = 8 (tile it, A then B). Issue A(it+1)
    // -> 12; vmcnt(4) drains the oldest 8 = tile it complete (FIFO). Last
    // iter issues nothing -> vmcnt(0).
    if (it + 1 < NIT) {
      issueA((it + 1) * 64, buf ^ 1);
      asm volatile("s_waitcnt vmcnt(4)\n\ts_barrier" ::: "memory");
    } else {
      asm volatile("s_waitcnt vmcnt(0)\n\ts_barrier" ::: "memory");
    }

    const u16* qa = pa + buf * 16384;
    const u16* qb = pb + buf * 16384;
    bf16x8 af0[4], bfr0[4], af1[4], bfr1[4];
    // hoist ALL fragment reads: kk1's latency hides under the kk0 MFMA cluster
#pragma unroll
    for (int t = 0; t < 4; ++t) {
      af0[t]  = *(const bf16x8*)(qa + t * 1024 + sk0);   // +16 rows * 64 stride
      bfr0[t] = *(const bf16x8*)(qb + t * 1024 + sk0);
      af1[t]  = *(const bf16x8*)(qa + t * 1024 + sk1);
      bfr1[t] = *(const bf16x8*)(qb + t * 1024 + sk1);
    }
    __builtin_amdgcn_s_setprio(1);
#pragma unroll
    for (int tm = 0; tm < 4; ++tm)
#pragma unroll
      for (int tn = 0; tn < 4; ++tn)
        acc[tm][tn] = __builtin_amdgcn_mfma_f32_16x16x32_bf16(af0[tm], bfr0[tn], acc[tm][tn], 0, 0, 0);
    __builtin_amdgcn_s_setprio(0);
    // issue B(it+1) under the MFMA shadow; targets buf^1, readers use buf -> safe
    if (it + 1 < NIT) issueB((it + 1) * 64, buf ^ 1);
    __builtin_amdgcn_s_setprio(1);
#pragma unroll
    for (int tm = 0; tm < 4; ++tm)
#pragma unroll
      for (int tn = 0; tn < 4; ++tn)
        acc[tm][tn] = __builtin_amdgcn_mfma_f32_16x16x32_bf16(af1[tm], bfr1[tn], acc[tm][tn], 0, 0, 0);
    __builtin_amdgcn_s_setprio(0);

    asm volatile("s_waitcnt lgkmcnt(0)\n\ts_barrier" ::: "memory");
  }

  // epilogue: D row = lq*4 + r, col = lr (m89-verified layout)
#pragma unroll
  for (int tm = 0; tm < 4; ++tm) {
    size_t rw = bm + waveM * 64 + tm * 16 + lq * 4;
#pragma unroll
    for (int tn = 0; tn < 4; ++tn) {
      int col = (int)bn + waveN * 64 + tn * 16 + lr;
      float bv = bias[col];
#pragma unroll
      for (int r = 0; r < 4; ++r) {
        float v = acc[tm][tn][r] + bv;
        if (RELU) v = fmaxf(v, 0.f);
        Cout[(rw + r) * ldc + col] = f2bf(v);
      }
    }
  }
}

// ---------------- sampling (512 thr, grid 2048; 4 rows/block) --------------------
// 8 waves = 4 row-pairs x {R,S}. Single register-resident pass: each lane loads a
// 16B ushort8 chunk (8 cols) once; max, S, T all from registers. R wave: bulk cols
// 0..511 + lane0 extra col 512. S wave: bulk cols 512..1023 with col 512 masked
// out (lane0 elem0), extras x1024 (lane63) and x1025 (lane0). r11: the h2 x W2c
// dot is now SPLIT across the R/S wave pair (each wave 512 elems, 8/lane),
// partials exchanged via a dedicated shd[] (no alias with shf[]: shf writes
// happen after the combine + a later barrier orders the final read). Halves the
// dot's serial cost (R wave previously idled). fp32-accum reorder is safe.
__global__ __launch_bounds__(512) void k_sample(const u16* __restrict__ lgts,
    const u16* __restrict__ h2, const u16* __restrict__ W2c,
    const float* __restrict__ b2,
    const int* __restrict__ idxR, const int* __restrict__ lenR,
    const int* __restrict__ idxS, const int* __restrict__ lenS,
    float* __restrict__ out) {
  __shared__ float shf[16];
  __shared__ float shd[16];   // dot partials: [pair*4 + grp*2 + {0,1}]
  const int tid = threadIdx.x;
  const int w = tid >> 6, lane = tid & 63;
  const int grp = w & 1, pair = w >> 1;
  const int row = blockIdx.x * 4 + pair;
  const u16* base = lgts + (size_t)row * LGN + (grp ? NHEAD : 0);
  const int* sidx = (grp ? idxS : idxR) + (size_t)row * KSEL;
  const int slen  = (grp ? lenS : lenR)[row];

  // both waves: partial h2 x W2c dot over their 512-elem half (8 elems/lane)
  {
    const bf16x8 hv = *(const bf16x8*)(h2 + (size_t)row * HID + grp * 512 + lane * 8);
    const bf16x8 a0 = *(const bf16x8*)(W2c + grp * 512 + lane * 8);
    const bf16x8 c0 = *(const bf16x8*)(W2c + 1024 + grp * 512 + lane * 8);
    float d0 = 0.f, d1 = 0.f;
#pragma unroll
    for (int j = 0; j < 8; ++j) {
      float h = bf2f((u16)hv[j]);
      d0 += h * bf2f((u16)a0[j]);
      d1 += h * bf2f((u16)c0[j]);
    }
#pragma unroll
    for (int dd = 32; dd; dd >>= 1) { d0 += __shfl_xor(d0, dd, 64); d1 += __shfl_xor(d1, dd, 64); }
    if (lane == 0) { shd[pair * 4 + grp * 2] = d0; shd[pair * 4 + grp * 2 + 1] = d1; }
  }
  __syncthreads();

  float x1024 = 0.f, x1025 = 0.f;
  if (grp) {
    x1024 = shd[pair * 4] + shd[pair * 4 + 2] + b2[1024];
    x1025 = shd[pair * 4 + 1] + shd[pair * 4 + 3] + b2[1025];
  }

  // bulk load: 8 cols/lane, one 16B load
  const u16* chunk = lgts + (size_t)row * LGN + (grp ? 512 : 0) + lane * 8;
  bf16x8 raw = *(const bf16x8*)chunk;
  float v[8];
#pragma unroll
  for (int j = 0; j < 8; ++j) v[j] = bf2f((u16)raw[j]);
  if (grp && lane == 0) v[0] = -3.4e38f;   // col 512 belongs to R

  // extra per-lane element (mirrors old lane assignment exactly)
  float xa = -3.4e38f; int has_xa = 0;
  if (!grp && lane == 0)  { xa = bf2f(base[512]); has_xa = 1; }  // R col 512
  if (grp  && lane == 63) { xa = x1024;           has_xa = 1; }
  if (grp  && lane == 0)  { xa = x1025;           has_xa = 1; }

  float m = -3.4e38f;
#pragma unroll
  for (int j = 0; j < 8; ++j) m = fmaxf(m, v[j]);
  if (has_xa) m = fmaxf(m, xa);
#pragma unroll
  for (int dd = 32; dd; dd >>= 1) m = fmaxf(m, __shfl_xor(m, dd, 64));

  float S = 0.f, T = 0.f;
#pragma unroll
  for (int j = 0; j < 8; ++j) {
    float e = __expf(v[j] - m);   // masked slots underflow to 0; 0*finite = 0
    S += e; T += e * v[j];
  }
  if (has_xa) { float e = __expf(xa - m); S += e; T += e * xa; }
#pragma unroll
  for (int dd = 32; dd; dd >>= 1) { S += __shfl_xor(S, dd, 64); T += __shfl_xor(T, dd, 64); }

  float e = 0.f, ex = 0.f, xt = 0.f;
  int active = (lane < KSEL) && (lane < slen);
  int valid = 0;
  if (active) {
    int id = sidx[lane];
    if (id >= 0) {
      valid = 1;
      if (grp && id >= 511) xt = (id == 511) ? x1024 : x1025;
      else                  xt = bf2f(base[id]);
      e  = __expf(xt - m);
      ex = e * xt;
    }
  }
  float pe = e, pex = ex;
#pragma unroll
  for (int dd = 1; dd < 32; dd <<= 1) {
    float qa = __shfl_up(pe, dd, 64);
    float qb = __shfl_up(pex, dd, 64);
    if (lane >= dd) { pe += qa; pex += qb; }
  }
  float lp = 0.f, en = 0.f;
  if (active) {
    float St = S - (pe - e);
    float Tt = T - (pex - ex);
    float logZ = m + __logf(St);
    en = logZ - Tt / St;
    if (valid) lp = xt - logZ;
  }
#pragma unroll
  for (int dd = 32; dd; dd >>= 1) { lp += __shfl_xor(lp, dd, 64); en += __shfl_xor(en, dd, 64); }

  if (lane == 0) { shf[w * 2] = lp; shf[w * 2 + 1] = en; }
  __syncthreads();
  if (lane == 0 && grp == 0) {
    out[row]         = shf[pair * 4] + shf[pair * 4 + 2];
    out[BATCH + row] = shf[pair * 4 + 1] + shf[pair * 4 + 3];
  }
}

// ---------------- launch ----------------
extern "C" void kernel_launch(void* const* d_in, const int* in_sizes, int n_in,
                              void* d_out, int out_size, void* d_ws, size_t ws_size,
                              hipStream_t stream) {
  (void)in_sizes; (void)n_in; (void)out_size; (void)ws_size;
  const float* state = (const float*)d_in[0];
  const float* W0 = (const float*)d_in[1];
  const float* b0 = (const float*)d_in[2];
  const float* W1 = (const float*)d_in[3];
  const float* b1 = (const float*)d_in[4];
  const float* W2 = (const float*)d_in[5];
  const float* b2 = (const float*)d_in[6];
  const int* idxR = (const int*)d_in[7];
  const int* lenR = (const int*)d_in[8];
  const int* idxS = (const int*)d_in[9];
  const int* lenS = (const int*)d_in[10];
  float* out = (float*)d_out;

  char* ws = (char*)d_ws;
  size_t off = 0;
  auto alloc = [&](size_t bytes) -> char* {
    char* p = ws + off;
    off = (off + bytes + 255) & ~(size_t)255;
    return p;
  };
  u16* As   = (u16*)alloc((size_t)BATCH * KP0 * 2);   // 17.8 MB
  u16* W0t  = (u16*)alloc((size_t)HID * KP0 * 2);     //  2.2 MB
  u16* W1t  = (u16*)alloc((size_t)HID * HID * 2);     //  2.1 MB
  u16* W2t  = (u16*)alloc((size_t)HID * LGN * 2);     //  2.1 MB
  u16* W2c  = (u16*)alloc((size_t)2 * 1024 * 2);      //  4 KB
  u16* h1   = (u16*)alloc((size_t)BATCH * HID * 2);   // 16.8 MB
  u16* h2   = (u16*)alloc((size_t)BATCH * HID * 2);   // 16.8 MB
  u16* lgts = (u16*)alloc((size_t)BATCH * LGN * 2);   // 16.8 MB

  k_cvt<<<4352, 512, 0, stream>>>(state, W0, W1, W2, As, W0t, W1t, W2t, W2c);

  gemm_bt<true,  KP0><<<512, 256, 0, stream>>>(As, W0t, b0, h1,   HID);
  gemm_bt<true,  HID><<<512, 256, 0, stream>>>(h1, W1t, b1, h2,   HID);
  gemm_bt<false, HID><<<512, 256, 0, stream>>>(h2, W2t, b2, lgts, LGN);

  k_sample<<<2048, 512, 0, stream>>>(lgts, h2, W2c, b2, idxR, lenR, idxS, lenS, out);
}

// Round 12
// 175.078 us; speedup vs baseline: 1.0118x; 1.0118x over previous
//
#include <hip/hip_runtime.h>
#include <cstdint>
#include <cstddef>

#define BATCH 8192
#define DIN   1025
#define HID   1024
#define NACT  1026
#define NHEAD 513
#define KSEL  32
#define KP0   1088   /* DIN padded to multiple of 64 */
#define LGN   1024   /* logits cols 0..1023 via GEMM; 1024/1025 computed in sample */

typedef unsigned short u16;
typedef short bf16x8 __attribute__((ext_vector_type(8)));
typedef float f32x4 __attribute__((ext_vector_type(4)));

__device__ __forceinline__ u16 f2bf(float f) {
  unsigned u = __float_as_uint(f);
  u += 0x7fff + ((u >> 16) & 1);   // round-to-nearest-even
  return (u16)(u >> 16);
}
__device__ __forceinline__ float bf2f(u16 h) {
  return __uint_as_float((unsigned)h << 16);
}

__device__ __forceinline__ void async_cp16(const u16* g, u16* l) {
  __builtin_amdgcn_global_load_lds((const __attribute__((address_space(1))) void*)g,
                                   (__attribute__((address_space(3))) void*)l,
                                   16, 0, 0);
}

// ---------------- conversion kernel (512 thr, grid 4352) ----------------
// blocks: state cvt one pass (4352*512*4 = BATCH*KP0); blocks 0..3136 also do one
// 32x32 weight-transpose tile each (W0t 1088, W1t 1024, W2t 1024, W2c 1).
__global__ __launch_bounds__(512) void k_cvt(const float* __restrict__ state,
    const float* __restrict__ W0, const float* __restrict__ W1,
    const float* __restrict__ W2,
    u16* __restrict__ As, u16* __restrict__ W0t, u16* __restrict__ W1t,
    u16* __restrict__ W2t, u16* __restrict__ W2c) {
  const int tid = threadIdx.x;
  const int b = blockIdx.x;
  // state f32 [B][DIN] -> bf16 [B][KP0], 4 elems/thread
  {
    int i = b * 512 + tid;
    const int QPR = KP0 / 4;   // 272
    int r = i / QPR, c4 = (i - r * QPR) * 4;
    const float* src = state + (size_t)r * DIN + c4;
    ushort4 o;
    if (c4 + 3 < DIN) {
      o.x = f2bf(src[0]); o.y = f2bf(src[1]); o.z = f2bf(src[2]); o.w = f2bf(src[3]);
    } else {
      o.x = (c4 + 0 < DIN) ? f2bf(src[0]) : 0;
      o.y = (c4 + 1 < DIN) ? f2bf(src[1]) : 0;
      o.z = (c4 + 2 < DIN) ? f2bf(src[2]) : 0;
      o.w = (c4 + 3 < DIN) ? f2bf(src[3]) : 0;
    }
    *(ushort4*)(As + (size_t)r * KP0 + c4) = o;
  }
  if (b >= 3137) return;
  if (b == 3136) {   // W2 cols 1024,1025 -> W2c[2][1024]
    for (int e = tid; e < 2048; e += 512) {
      int j = e >> 10, k = e & 1023;
      W2c[e] = f2bf(W2[(size_t)k * NACT + 1024 + j]);
    }
    return;
  }
  const float* W; u16* Wt; int K, ldW, Kp, tt = b;
  if (tt < 1088)      { W = W0; Wt = W0t; K = DIN; ldW = HID;  Kp = KP0; }
  else if (tt < 2112) { tt -= 1088; W = W1; Wt = W1t; K = HID; ldW = HID;  Kp = HID; }
  else                { tt -= 2112; W = W2; Wt = W2t; K = HID; ldW = NACT; Kp = HID; }
  int n0 = (tt & 31) * 32, k0 = (tt >> 5) * 32;
  __shared__ float tile[32][33];
  const int tx = tid & 31, ty = tid >> 5;   // ty 0..15
#pragma unroll
  for (int i = 0; i < 32; i += 16) {
    int k = k0 + ty + i;
    tile[ty + i][tx] = (k < K) ? W[(size_t)k * ldW + n0 + tx] : 0.f;
  }
  __syncthreads();
#pragma unroll
  for (int i = 0; i < 32; i += 16)
    Wt[(size_t)(n0 + ty + i) * Kp + k0 + tx] = f2bf(tile[tx][ty + i]);
}

// ---- GEMM: block tile 128x128, 256 thr = 4 waves (2M x 2N, 64x64 each) ---------
// C[M][ldc] = A[M][K]*Bt[N][K]^T (+bias, relu). BK=64. SESSION RESULT (r10,
// 175.8 us; 12 configs bracketed it; r11's hoist/dot-split variants reverted per
// pre-commitment at 177.2). GEMM ~21-22 us/layer ~ 800 TF. 2 blocks/CU (grid
// 512, 64KB LDS dbuf): the co-resident block hides each barrier drain (m114);
// reads/MFMA analysis: every full-chip alternative forces a worse wave shape,
// every better wave shape forces a half-chip grid at N=1024.
//  (1) T5 setprio(1/0) around each 16-MFMA cluster -- with 2 independent
//      blocks/CU there IS wave-role diversity to arbitrate (unlike m190's
//      lockstep null). Measured +~1us/GEMM together with (2).
//  (2) split staging issue: A-chunks at iter start w/ vmcnt(4) (FIFO: oldest
//      8 = tile it's dma, identical safety to vmcnt(8)-after-8), B-chunks
//      issued under the kk0 MFMA shadow. No barrier/buffer/swizzle change.
// Bank swizzle (r4-PMC-verified 0-conflict): chunk c -> row c>>3, slot c&7,
// source kchunk g = slot^(row&7); read slot (kk*4+lq)^(lr&7).
template<bool RELU, int K>
__global__ __launch_bounds__(256, 2)
void gemm_bt(const u16* __restrict__ A, const u16* __restrict__ Bt,
             const float* __restrict__ bias, u16* __restrict__ Cout, int ldc)
{
  __shared__ __align__(16) u16 lds[32768];   // 2 bufs x (A 8192 + B 8192 u16) = 64 KB

  const int d     = blockIdx.x;
  const int m8    = d & 7;
  const int ntile = (d >> 3) & 7;
  const int mtile = ((d >> 6) << 3) | m8;
  const size_t bm = (size_t)mtile * 128;
  const size_t bn = (size_t)ntile * 128;

  const int tid  = threadIdx.x;
  const int wave = tid >> 6;
  const int lane = tid & 63;
  const int waveM = wave >> 1, waveN = wave & 1;   // 2 x 2 waves, 64x64 each
  const int lr = lane & 15, lq = lane >> 4;

  // staging (per thread, 8 chunks of 16B): chunk c (0..1023 per matrix) ->
  // row = c>>3, slot = c&7, source kchunk g = slot ^ (row&7). Thread t handles
  // c = t + 256k, k=0..3: row = (t>>3)+32k (row&7 const), slot = t&7 const ->
  // g_ = (t&7) ^ ((t>>3)&7) constant per thread. LDS dest is linear (c*16B),
  // satisfying global_load_lds's wave-uniform-base+lane*16 rule.
  const int row0 = tid >> 3;                       // 0..31
  const int g_   = (tid & 7) ^ ((tid >> 3) & 7);
  const u16* gA0 = A  + (bm + row0)      * (size_t)K + g_ * 8;
  const u16* gA1 = A  + (bm + row0 + 32) * (size_t)K + g_ * 8;
  const u16* gA2 = A  + (bm + row0 + 64) * (size_t)K + g_ * 8;
  const u16* gA3 = A  + (bm + row0 + 96) * (size_t)K + g_ * 8;
  const u16* gB0 = Bt + (bn + row0)      * (size_t)K + g_ * 8;
  const u16* gB1 = Bt + (bn + row0 + 32) * (size_t)K + g_ * 8;
  const u16* gB2 = Bt + (bn + row0 + 64) * (size_t)K + g_ * 8;
  const u16* gB3 = Bt + (bn + row0 + 96) * (size_t)K + g_ * 8;
  u16* lA = lds + wave * 512;          // + 2048*k per chunk; +buf*16384
  u16* lB = lds + 8192 + wave * 512;

  f32x4 acc[4][4] = {};

  // fragment read: row = base16 + lr so row&7 = lr&7 = xr. For k-half kk the
  // wanted kchunk g* = kk*4+lq sits at slot (kk*4+lq)^xr.
  const int xr  = lane & 7;
  const int sk0 = ((0 | lq) ^ xr) * 8;   // u16 offset within row, kk=0
  const int sk1 = ((4 | lq) ^ xr) * 8;   // kk=1
  const u16* pa = lds + (waveM * 64 + lr) * 64;
  const u16* pb = lds + 8192 + (waveN * 64 + lr) * 64;

  auto issueA = [&](int k0, int buf) {
    const int o = buf * 16384;
    async_cp16(gA0 + k0, lA + o);
    async_cp16(gA1 + k0, lA + o + 2048);
    async_cp16(gA2 + k0, lA + o + 4096);
    async_cp16(gA3 + k0, lA + o + 6144);
  };
  auto issueB = [&](int k0, int buf) {
    const int o = buf * 16384;
    async_cp16(gB0 + k0, lB + o);
    async_cp16(gB1 + k0, lB + o + 2048);
    async_cp16(gB2 + k0, lB + o + 4096);
    async_cp16(gB3 + k0, lB + o + 6144);
  };

  const int NIT = K / 64;
  issueA(0, 0);
  issueB(0, 0);
#pragma unroll 2
  for (int it = 0; it < NIT; ++it) {
    const int buf = it & 1;
    // Ledger: at iter entry in-flight = 8 (tile it, A then B). Issue A(it+1)
    // -> 12; vmcnt(4) drains the oldest 8 = tile it complete (FIFO). Last
    // iter issues nothing -> vmcnt(0).
    if (it + 1 < NIT) {
      issueA((it + 1) * 64, buf ^ 1);
      asm volatile("s_waitcnt vmcnt(4)\n\ts_barrier" ::: "memory");
    } else {
      asm volatile("s_waitcnt vmcnt(0)\n\ts_barrier" ::: "memory");
    }

    const u16* qa = pa + buf * 16384;
    const u16* qb = pb + buf * 16384;
    bf16x8 af[4], bfr[4];
    // kk = 0 half (k 0..31 of the slab)
#pragma unroll
    for (int t = 0; t < 4; ++t) {
      af[t]  = *(const bf16x8*)(qa + t * 1024 + sk0);   // +16 rows * 64 stride
      bfr[t] = *(const bf16x8*)(qb + t * 1024 + sk0);
    }
    __builtin_amdgcn_s_setprio(1);
#pragma unroll
    for (int tm = 0; tm < 4; ++tm)
#pragma unroll
      for (int tn = 0; tn < 4; ++tn)
        acc[tm][tn] = __builtin_amdgcn_mfma_f32_16x16x32_bf16(af[tm], bfr[tn], acc[tm][tn], 0, 0, 0);
    __builtin_amdgcn_s_setprio(0);
    // issue B(it+1) under the MFMA shadow; targets buf^1, readers use buf -> safe
    if (it + 1 < NIT) issueB((it + 1) * 64, buf ^ 1);
    // kk = 1 half (k 32..63)
#pragma unroll
    for (int t = 0; t < 4; ++t) {
      af[t]  = *(const bf16x8*)(qa + t * 1024 + sk1);
      bfr[t] = *(const bf16x8*)(qb + t * 1024 + sk1);
    }
    __builtin_amdgcn_s_setprio(1);
#pragma unroll
    for (int tm = 0; tm < 4; ++tm)
#pragma unroll
      for (int tn = 0; tn < 4; ++tn)
        acc[tm][tn] = __builtin_amdgcn_mfma_f32_16x16x32_bf16(af[tm], bfr[tn], acc[tm][tn], 0, 0, 0);
    __builtin_amdgcn_s_setprio(0);

    asm volatile("s_waitcnt lgkmcnt(0)\n\ts_barrier" ::: "memory");
  }

  // epilogue: D row = lq*4 + r, col = lr (m89-verified layout)
#pragma unroll
  for (int tm = 0; tm < 4; ++tm) {
    size_t rw = bm + waveM * 64 + tm * 16 + lq * 4;
#pragma unroll
    for (int tn = 0; tn < 4; ++tn) {
      int col = (int)bn + waveN * 64 + tn * 16 + lr;
      float bv = bias[col];
#pragma unroll
      for (int r = 0; r < 4; ++r) {
        float v = acc[tm][tn][r] + bv;
        if (RELU) v = fmaxf(v, 0.f);
        Cout[(rw + r) * ldc + col] = f2bf(v);
      }
    }
  }
}

// ---------------- sampling (512 thr, grid 2048; 4 rows/block) --------------------
// 8 waves = 4 row-pairs x {R,S}. Single register-resident pass: each lane loads a
// 16B ushort8 chunk (8 cols) once; max, S, T all from registers. R wave: bulk cols
// 0..511 + lane0 extra col 512. S wave: bulk cols 512..1023 with col 512 masked
// out (lane0 elem0), extras x1024 (lane63) and x1025 (lane0) from the vectorized
// h2 x W2c dot. Verified math kept.
__global__ __launch_bounds__(512) void k_sample(const u16* __restrict__ lgts,
    const u16* __restrict__ h2, const u16* __restrict__ W2c,
    const float* __restrict__ b2,
    const int* __restrict__ idxR, const int* __restrict__ lenR,
    const int* __restrict__ idxS, const int* __restrict__ lenS,
    float* __restrict__ out) {
  __shared__ float shf[16];
  const int tid = threadIdx.x;
  const int w = tid >> 6, lane = tid & 63;
  const int grp = w & 1, pair = w >> 1;
  const int row = blockIdx.x * 4 + pair;
  const u16* base = lgts + (size_t)row * LGN + (grp ? NHEAD : 0);
  const int* sidx = (grp ? idxS : idxR) + (size_t)row * KSEL;
  const int slen  = (grp ? lenS : lenR)[row];

  float x1024 = 0.f, x1025 = 0.f;
  if (grp) {
    const bf16x8* hp  = (const bf16x8*)(h2 + (size_t)row * HID + lane * 16);
    const bf16x8* w0p = (const bf16x8*)(W2c + lane * 16);
    const bf16x8* w1p = (const bf16x8*)(W2c + 1024 + lane * 16);
    bf16x8 hv0 = hp[0],  hv1 = hp[1];
    bf16x8 a0  = w0p[0], a1  = w0p[1];
    bf16x8 c0  = w1p[0], c1  = w1p[1];
    float d0 = 0.f, d1 = 0.f;
#pragma unroll
    for (int j = 0; j < 8; ++j) {
      float h0 = bf2f((u16)hv0[j]);
      float h1 = bf2f((u16)hv1[j]);
      d0 += h0 * bf2f((u16)a0[j]) + h1 * bf2f((u16)a1[j]);
      d1 += h0 * bf2f((u16)c0[j]) + h1 * bf2f((u16)c1[j]);
    }
#pragma unroll
    for (int dd = 32; dd; dd >>= 1) { d0 += __shfl_xor(d0, dd, 64); d1 += __shfl_xor(d1, dd, 64); }
    x1024 = d0 + b2[1024];
    x1025 = d1 + b2[1025];
  }

  // bulk load: 8 cols/lane, one 16B load
  const u16* chunk = lgts + (size_t)row * LGN + (grp ? 512 : 0) + lane * 8;
  bf16x8 raw = *(const bf16x8*)chunk;
  float v[8];
#pragma unroll
  for (int j = 0; j < 8; ++j) v[j] = bf2f((u16)raw[j]);
  if (grp && lane == 0) v[0] = -3.4e38f;   // col 512 belongs to R

  // extra per-lane element (mirrors old lane assignment exactly)
  float xa = -3.4e38f; int has_xa = 0;
  if (!grp && lane == 0)  { xa = bf2f(base[512]); has_xa = 1; }  // R col 512
  if (grp  && lane == 63) { xa = x1024;           has_xa = 1; }
  if (grp  && lane == 0)  { xa = x1025;           has_xa = 1; }

  float m = -3.4e38f;
#pragma unroll
  for (int j = 0; j < 8; ++j) m = fmaxf(m, v[j]);
  if (has_xa) m = fmaxf(m, xa);
#pragma unroll
  for (int dd = 32; dd; dd >>= 1) m = fmaxf(m, __shfl_xor(m, dd, 64));

  float S = 0.f, T = 0.f;
#pragma unroll
  for (int j = 0; j < 8; ++j) {
    float e = __expf(v[j] - m);   // masked slots underflow to 0; 0*finite = 0
    S += e; T += e * v[j];
  }
  if (has_xa) { float e = __expf(xa - m); S += e; T += e * xa; }
#pragma unroll
  for (int dd = 32; dd; dd >>= 1) { S += __shfl_xor(S, dd, 64); T += __shfl_xor(T, dd, 64); }

  float e = 0.f, ex = 0.f, xt = 0.f;
  int active = (lane < KSEL) && (lane < slen);
  int valid = 0;
  if (active) {
    int id = sidx[lane];
    if (id >= 0) {
      valid = 1;
      if (grp && id >= 511) xt = (id == 511) ? x1024 : x1025;
      else                  xt = bf2f(base[id]);
      e  = __expf(xt - m);
      ex = e * xt;
    }
  }
  float pe = e, pex = ex;
#pragma unroll
  for (int dd = 1; dd < 32; dd <<= 1) {
    float qa = __shfl_up(pe, dd, 64);
    float qb = __shfl_up(pex, dd, 64);
    if (lane >= dd) { pe += qa; pex += qb; }
  }
  float lp = 0.f, en = 0.f;
  if (active) {
    float St = S - (pe - e);
    float Tt = T - (pex - ex);
    float logZ = m + __logf(St);
    en = logZ - Tt / St;
    if (valid) lp = xt - logZ;
  }
#pragma unroll
  for (int dd = 32; dd; dd >>= 1) { lp += __shfl_xor(lp, dd, 64); en += __shfl_xor(en, dd, 64); }

  if (lane == 0) { shf[w * 2] = lp; shf[w * 2 + 1] = en; }
  __syncthreads();
  if (lane == 0 && grp == 0) {
    out[row]         = shf[pair * 4] + shf[pair * 4 + 2];
    out[BATCH + row] = shf[pair * 4 + 1] + shf[pair * 4 + 3];
  }
}

// ---------------- launch ----------------
extern "C" void kernel_launch(void* const* d_in, const int* in_sizes, int n_in,
                              void* d_out, int out_size, void* d_ws, size_t ws_size,
                              hipStream_t stream) {
  (void)in_sizes; (void)n_in; (void)out_size; (void)ws_size;
  const float* state = (const float*)d_in[0];
  const float* W0 = (const float*)d_in[1];
  const float* b0 = (const float*)d_in[2];
  const float* W1 = (const float*)d_in[3];
  const float* b1 = (const float*)d_in[4];
  const float* W2 = (const float*)d_in[5];
  const float* b2 = (const float*)d_in[6];
  const int* idxR = (const int*)d_in[7];
  const int* lenR = (const int*)d_in[8];
  const int* idxS = (const int*)d_in[9];
  const int* lenS = (const int*)d_in[10];
  float* out = (float*)d_out;

  char* ws = (char*)d_ws;
  size_t off = 0;
  auto alloc = [&](size_t bytes) -> char* {
    char* p = ws + off;
    off = (off + bytes + 255) & ~(size_t)255;
    return p;
  };
  u16* As   = (u16*)alloc((size_t)BATCH * KP0 * 2);   // 17.8 MB
  u16* W0t  = (u16*)alloc((size_t)HID * KP0 * 2);     //  2.2 MB
  u16* W1t  = (u16*)alloc((size_t)HID * HID * 2);     //  2.1 MB
  u16* W2t  = (u16*)alloc((size_t)HID * LGN * 2);     //  2.1 MB
  u16* W2c  = (u16*)alloc((size_t)2 * 1024 * 2);      //  4 KB
  u16* h1   = (u16*)alloc((size_t)BATCH * HID * 2);   // 16.8 MB
  u16* h2   = (u16*)alloc((size_t)BATCH * HID * 2);   // 16.8 MB
  u16* lgts = (u16*)alloc((size_t)BATCH * LGN * 2);   // 16.8 MB

  k_cvt<<<4352, 512, 0, stream>>>(state, W0, W1, W2, As, W0t, W1t, W2t, W2c);

  gemm_bt<true,  KP0><<<512, 256, 0, stream>>>(As, W0t, b0, h1,   HID);
  gemm_bt<true,  HID><<<512, 256, 0, stream>>>(h1, W1t, b1, h2,   HID);
  gemm_bt<false, HID><<<512, 256, 0, stream>>>(h2, W2t, b2, lgts, LGN);

  k_sample<<<2048, 512, 0, stream>>>(lgts, h2, W2c, b2, idxR, lenR, idxS, lenS, out);
}

// Round 13
// 174.297 us; speedup vs baseline: 1.0164x; 1.0045x over previous
//
#include <hip/hip_runtime.h>
#include <cstdint>
#include <cstddef>

#define BATCH 8192
#define DIN   1025
#define HID   1024
#define NACT  1026
#define NHEAD 513
#define KSEL  32
#define KP0   1088   /* DIN padded to multiple of 64 */
#define LGN   1024   /* logits cols 0..1023 via GEMM; 1024/1025 computed in sample */

typedef unsigned short u16;
typedef short bf16x8 __attribute__((ext_vector_type(8)));
typedef float f32x4 __attribute__((ext_vector_type(4)));

__device__ __forceinline__ u16 f2bf(float f) {
  unsigned u = __float_as_uint(f);
  u += 0x7fff + ((u >> 16) & 1);   // round-to-nearest-even
  return (u16)(u >> 16);
}
__device__ __forceinline__ float bf2f(u16 h) {
  return __uint_as_float((unsigned)h << 16);
}

__device__ __forceinline__ void async_cp16(const u16* g, u16* l) {
  __builtin_amdgcn_global_load_lds((const __attribute__((address_space(1))) void*)g,
                                   (__attribute__((address_space(3))) void*)l,
                                   16, 0, 0);
}

// ---------------- conversion kernel (512 thr, grid 7489) ----------------
// r13: task-split load balance. Previously blocks 0..3136 ran TWO serial phases
// (state cvt -> syncthreads -> 32x32 weight-transpose) while 3137..4351 exited
// early -- the transpose work was serialized behind state cvt inside each block.
// Now every block does exactly ONE task: b < 4352 state cvt (4352*512*4 =
// BATCH*KP0 elems), b >= 4352: tt = b-4352 -> transpose tile tt (W0t 1088,
// W1t 1024, W2t 1024) or W2c (tt == 3136). Same total bytes; scheduler
// interleaves the two task types across the chip.
__global__ __launch_bounds__(512) void k_cvt(const float* __restrict__ state,
    const float* __restrict__ W0, const float* __restrict__ W1,
    const float* __restrict__ W2,
    u16* __restrict__ As, u16* __restrict__ W0t, u16* __restrict__ W1t,
    u16* __restrict__ W2t, u16* __restrict__ W2c) {
  const int tid = threadIdx.x;
  const int b = blockIdx.x;
  if (b < 4352) {
    // state f32 [B][DIN] -> bf16 [B][KP0], 4 elems/thread
    int i = b * 512 + tid;
    const int QPR = KP0 / 4;   // 272
    int r = i / QPR, c4 = (i - r * QPR) * 4;
    const float* src = state + (size_t)r * DIN + c4;
    ushort4 o;
    if (c4 + 3 < DIN) {
      o.x = f2bf(src[0]); o.y = f2bf(src[1]); o.z = f2bf(src[2]); o.w = f2bf(src[3]);
    } else {
      o.x = (c4 + 0 < DIN) ? f2bf(src[0]) : 0;
      o.y = (c4 + 1 < DIN) ? f2bf(src[1]) : 0;
      o.z = (c4 + 2 < DIN) ? f2bf(src[2]) : 0;
      o.w = (c4 + 3 < DIN) ? f2bf(src[3]) : 0;
    }
    *(ushort4*)(As + (size_t)r * KP0 + c4) = o;
    return;
  }
  int tt = b - 4352;
  if (tt == 3136) {   // W2 cols 1024,1025 -> W2c[2][1024]
    for (int e = tid; e < 2048; e += 512) {
      int j = e >> 10, k = e & 1023;
      W2c[e] = f2bf(W2[(size_t)k * NACT + 1024 + j]);
    }
    return;
  }
  const float* W; u16* Wt; int K, ldW, Kp;
  if (tt < 1088)      { W = W0; Wt = W0t; K = DIN; ldW = HID;  Kp = KP0; }
  else if (tt < 2112) { tt -= 1088; W = W1; Wt = W1t; K = HID; ldW = HID;  Kp = HID; }
  else                { tt -= 2112; W = W2; Wt = W2t; K = HID; ldW = NACT; Kp = HID; }
  int n0 = (tt & 31) * 32, k0 = (tt >> 5) * 32;
  __shared__ float tile[32][33];
  const int tx = tid & 31, ty = tid >> 5;   // ty 0..15
#pragma unroll
  for (int i = 0; i < 32; i += 16) {
    int k = k0 + ty + i;
    tile[ty + i][tx] = (k < K) ? W[(size_t)k * ldW + n0 + tx] : 0.f;
  }
  __syncthreads();
#pragma unroll
  for (int i = 0; i < 32; i += 16)
    Wt[(size_t)(n0 + ty + i) * Kp + k0 + tx] = f2bf(tile[tx][ty + i]);
}

// ---- GEMM: block tile 128x128, 256 thr = 4 waves (2M x 2N, 64x64 each) ---------
// C[M][ldc] = A[M][K]*Bt[N][K]^T (+bias, relu). BK=64. SESSION RESULT (r10,
// 175.8 us; reproduced r12 175.1; 12 configs bracketed it). GEMM ~21-22 us/layer
// ~ 800 TF. 2 blocks/CU (grid 512, 64KB LDS dbuf): the co-resident block hides
// each barrier drain (m114); reads/MFMA analysis: every full-chip alternative
// forces a worse wave shape, every better wave shape forces a half-chip grid at
// N=1024.
//  (1) T5 setprio(1/0) around each 16-MFMA cluster -- with 2 independent
//      blocks/CU there IS wave-role diversity to arbitrate (unlike m190's
//      lockstep null). Measured +~1us/GEMM together with (2).
//  (2) split staging issue: A-chunks at iter start w/ vmcnt(4) (FIFO: oldest
//      8 = tile it's dma, identical safety to vmcnt(8)-after-8), B-chunks
//      issued under the kk0 MFMA shadow. No barrier/buffer/swizzle change.
// Bank swizzle (r4-PMC-verified 0-conflict): chunk c -> row c>>3, slot c&7,
// source kchunk g = slot^(row&7); read slot (kk*4+lq)^(lr&7).
template<bool RELU, int K>
__global__ __launch_bounds__(256, 2)
void gemm_bt(const u16* __restrict__ A, const u16* __restrict__ Bt,
             const float* __restrict__ bias, u16* __restrict__ Cout, int ldc)
{
  __shared__ __align__(16) u16 lds[32768];   // 2 bufs x (A 8192 + B 8192 u16) = 64 KB

  const int d     = blockIdx.x;
  const int m8    = d & 7;
  const int ntile = (d >> 3) & 7;
  const int mtile = ((d >> 6) << 3) | m8;
  const size_t bm = (size_t)mtile * 128;
  const size_t bn = (size_t)ntile * 128;

  const int tid  = threadIdx.x;
  const int wave = tid >> 6;
  const int lane = tid & 63;
  const int waveM = wave >> 1, waveN = wave & 1;   // 2 x 2 waves, 64x64 each
  const int lr = lane & 15, lq = lane >> 4;

  // staging (per thread, 8 chunks of 16B): chunk c (0..1023 per matrix) ->
  // row = c>>3, slot = c&7, source kchunk g = slot ^ (row&7). Thread t handles
  // c = t + 256k, k=0..3: row = (t>>3)+32k (row&7 const), slot = t&7 const ->
  // g_ = (t&7) ^ ((t>>3)&7) constant per thread. LDS dest is linear (c*16B),
  // satisfying global_load_lds's wave-uniform-base+lane*16 rule.
  const int row0 = tid >> 3;                       // 0..31
  const int g_   = (tid & 7) ^ ((tid >> 3) & 7);
  const u16* gA0 = A  + (bm + row0)      * (size_t)K + g_ * 8;
  const u16* gA1 = A  + (bm + row0 + 32) * (size_t)K + g_ * 8;
  const u16* gA2 = A  + (bm + row0 + 64) * (size_t)K + g_ * 8;
  const u16* gA3 = A  + (bm + row0 + 96) * (size_t)K + g_ * 8;
  const u16* gB0 = Bt + (bn + row0)      * (size_t)K + g_ * 8;
  const u16* gB1 = Bt + (bn + row0 + 32) * (size_t)K + g_ * 8;
  const u16* gB2 = Bt + (bn + row0 + 64) * (size_t)K + g_ * 8;
  const u16* gB3 = Bt + (bn + row0 + 96) * (size_t)K + g_ * 8;
  u16* lA = lds + wave * 512;          // + 2048*k per chunk; +buf*16384
  u16* lB = lds + 8192 + wave * 512;

  f32x4 acc[4][4] = {};

  // fragment read: row = base16 + lr so row&7 = lr&7 = xr. For k-half kk the
  // wanted kchunk g* = kk*4+lq sits at slot (kk*4+lq)^xr.
  const int xr  = lane & 7;
  const int sk0 = ((0 | lq) ^ xr) * 8;   // u16 offset within row, kk=0
  const int sk1 = ((4 | lq) ^ xr) * 8;   // kk=1
  const u16* pa = lds + (waveM * 64 + lr) * 64;
  const u16* pb = lds + 8192 + (waveN * 64 + lr) * 64;

  auto issueA = [&](int k0, int buf) {
    const int o = buf * 16384;
    async_cp16(gA0 + k0, lA + o);
    async_cp16(gA1 + k0, lA + o + 2048);
    async_cp16(gA2 + k0, lA + o + 4096);
    async_cp16(gA3 + k0, lA + o + 6144);
  };
  auto issueB = [&](int k0, int buf) {
    const int o = buf * 16384;
    async_cp16(gB0 + k0, lB + o);
    async_cp16(gB1 + k0, lB + o + 2048);
    async_cp16(gB2 + k0, lB + o + 4096);
    async_cp16(gB3 + k0, lB + o + 6144);
  };

  const int NIT = K / 64;
  issueA(0, 0);
  issueB(0, 0);
#pragma unroll 2
  for (int it = 0; it < NIT; ++it) {
    const int buf = it & 1;
    // Ledger: at iter entry in-flight = 8 (tile it, A then B). Issue A(it+1)
    // -> 12; vmcnt(4) drains the oldest 8 = tile it complete (FIFO). Last
    // iter issues nothing -> vmcnt(0).
    if (it + 1 < NIT) {
      issueA((it + 1) * 64, buf ^ 1);
      asm volatile("s_waitcnt vmcnt(4)\n\ts_barrier" ::: "memory");
    } else {
      asm volatile("s_waitcnt vmcnt(0)\n\ts_barrier" ::: "memory");
    }

    const u16* qa = pa + buf * 16384;
    const u16* qb = pb + buf * 16384;
    bf16x8 af[4], bfr[4];
    // kk = 0 half (k 0..31 of the slab)
#pragma unroll
    for (int t = 0; t < 4; ++t) {
      af[t]  = *(const bf16x8*)(qa + t * 1024 + sk0);   // +16 rows * 64 stride
      bfr[t] = *(const bf16x8*)(qb + t * 1024 + sk0);
    }
    __builtin_amdgcn_s_setprio(1);
#pragma unroll
    for (int tm = 0; tm < 4; ++tm)
#pragma unroll
      for (int tn = 0; tn < 4; ++tn)
        acc[tm][tn] = __builtin_amdgcn_mfma_f32_16x16x32_bf16(af[tm], bfr[tn], acc[tm][tn], 0, 0, 0);
    __builtin_amdgcn_s_setprio(0);
    // issue B(it+1) under the MFMA shadow; targets buf^1, readers use buf -> safe
    if (it + 1 < NIT) issueB((it + 1) * 64, buf ^ 1);
    // kk = 1 half (k 32..63)
#pragma unroll
    for (int t = 0; t < 4; ++t) {
      af[t]  = *(const bf16x8*)(qa + t * 1024 + sk1);
      bfr[t] = *(const bf16x8*)(qb + t * 1024 + sk1);
    }
    __builtin_amdgcn_s_setprio(1);
#pragma unroll
    for (int tm = 0; tm < 4; ++tm)
#pragma unroll
      for (int tn = 0; tn < 4; ++tn)
        acc[tm][tn] = __builtin_amdgcn_mfma_f32_16x16x32_bf16(af[tm], bfr[tn], acc[tm][tn], 0, 0, 0);
    __builtin_amdgcn_s_setprio(0);

    asm volatile("s_waitcnt lgkmcnt(0)\n\ts_barrier" ::: "memory");
  }

  // epilogue: D row = lq*4 + r, col = lr (m89-verified layout)
#pragma unroll
  for (int tm = 0; tm < 4; ++tm) {
    size_t rw = bm + waveM * 64 + tm * 16 + lq * 4;
#pragma unroll
    for (int tn = 0; tn < 4; ++tn) {
      int col = (int)bn + waveN * 64 + tn * 16 + lr;
      float bv = bias[col];
#pragma unroll
      for (int r = 0; r < 4; ++r) {
        float v = acc[tm][tn][r] + bv;
        if (RELU) v = fmaxf(v, 0.f);
        Cout[(rw + r) * ldc + col] = f2bf(v);
      }
    }
  }
}

// ---------------- sampling (512 thr, grid 2048; 4 rows/block) --------------------
// 8 waves = 4 row-pairs x {R,S}. Single register-resident pass: each lane loads a
// 16B ushort8 chunk (8 cols) once; max, S, T all from registers. R wave: bulk cols
// 0..511 + lane0 extra col 512. S wave: bulk cols 512..1023 with col 512 masked
// out (lane0 elem0), extras x1024 (lane63) and x1025 (lane0) from the vectorized
// h2 x W2c dot. Verified math kept.
__global__ __launch_bounds__(512) void k_sample(const u16* __restrict__ lgts,
    const u16* __restrict__ h2, const u16* __restrict__ W2c,
    const float* __restrict__ b2,
    const int* __restrict__ idxR, const int* __restrict__ lenR,
    const int* __restrict__ idxS, const int* __restrict__ lenS,
    float* __restrict__ out) {
  __shared__ float shf[16];
  const int tid = threadIdx.x;
  const int w = tid >> 6, lane = tid & 63;
  const int grp = w & 1, pair = w >> 1;
  const int row = blockIdx.x * 4 + pair;
  const u16* base = lgts + (size_t)row * LGN + (grp ? NHEAD : 0);
  const int* sidx = (grp ? idxS : idxR) + (size_t)row * KSEL;
  const int slen  = (grp ? lenS : lenR)[row];

  float x1024 = 0.f, x1025 = 0.f;
  if (grp) {
    const bf16x8* hp  = (const bf16x8*)(h2 + (size_t)row * HID + lane * 16);
    const bf16x8* w0p = (const bf16x8*)(W2c + lane * 16);
    const bf16x8* w1p = (const bf16x8*)(W2c + 1024 + lane * 16);
    bf16x8 hv0 = hp[0],  hv1 = hp[1];
    bf16x8 a0  = w0p[0], a1  = w0p[1];
    bf16x8 c0  = w1p[0], c1  = w1p[1];
    float d0 = 0.f, d1 = 0.f;
#pragma unroll
    for (int j = 0; j < 8; ++j) {
      float h0 = bf2f((u16)hv0[j]);
      float h1 = bf2f((u16)hv1[j]);
      d0 += h0 * bf2f((u16)a0[j]) + h1 * bf2f((u16)a1[j]);
      d1 += h0 * bf2f((u16)c0[j]) + h1 * bf2f((u16)c1[j]);
    }
#pragma unroll
    for (int dd = 32; dd; dd >>= 1) { d0 += __shfl_xor(d0, dd, 64); d1 += __shfl_xor(d1, dd, 64); }
    x1024 = d0 + b2[1024];
    x1025 = d1 + b2[1025];
  }

  // bulk load: 8 cols/lane, one 16B load
  const u16* chunk = lgts + (size_t)row * LGN + (grp ? 512 : 0) + lane * 8;
  bf16x8 raw = *(const bf16x8*)chunk;
  float v[8];
#pragma unroll
  for (int j = 0; j < 8; ++j) v[j] = bf2f((u16)raw[j]);
  if (grp && lane == 0) v[0] = -3.4e38f;   // col 512 belongs to R

  // extra per-lane element (mirrors old lane assignment exactly)
  float xa = -3.4e38f; int has_xa = 0;
  if (!grp && lane == 0)  { xa = bf2f(base[512]); has_xa = 1; }  // R col 512
  if (grp  && lane == 63) { xa = x1024;           has_xa = 1; }
  if (grp  && lane == 0)  { xa = x1025;           has_xa = 1; }

  float m = -3.4e38f;
#pragma unroll
  for (int j = 0; j < 8; ++j) m = fmaxf(m, v[j]);
  if (has_xa) m = fmaxf(m, xa);
#pragma unroll
  for (int dd = 32; dd; dd >>= 1) m = fmaxf(m, __shfl_xor(m, dd, 64));

  float S = 0.f, T = 0.f;
#pragma unroll
  for (int j = 0; j < 8; ++j) {
    float e = __expf(v[j] - m);   // masked slots underflow to 0; 0*finite = 0
    S += e; T += e * v[j];
  }
  if (has_xa) { float e = __expf(xa - m); S += e; T += e * xa; }
#pragma unroll
  for (int dd = 32; dd; dd >>= 1) { S += __shfl_xor(S, dd, 64); T += __shfl_xor(T, dd, 64); }

  float e = 0.f, ex = 0.f, xt = 0.f;
  int active = (lane < KSEL) && (lane < slen);
  int valid = 0;
  if (active) {
    int id = sidx[lane];
    if (id >= 0) {
      valid = 1;
      if (grp && id >= 511) xt = (id == 511) ? x1024 : x1025;
      else                  xt = bf2f(base[id]);
      e  = __expf(xt - m);
      ex = e * xt;
    }
  }
  float pe = e, pex = ex;
#pragma unroll
  for (int dd = 1; dd < 32; dd <<= 1) {
    float qa = __shfl_up(pe, dd, 64);
    float qb = __shfl_up(pex, dd, 64);
    if (lane >= dd) { pe += qa; pex += qb; }
  }
  float lp = 0.f, en = 0.f;
  if (active) {
    float St = S - (pe - e);
    float Tt = T - (pex - ex);
    float logZ = m + __logf(St);
    en = logZ - Tt / St;
    if (valid) lp = xt - logZ;
  }
#pragma unroll
  for (int dd = 32; dd; dd >>= 1) { lp += __shfl_xor(lp, dd, 64); en += __shfl_xor(en, dd, 64); }

  if (lane == 0) { shf[w * 2] = lp; shf[w * 2 + 1] = en; }
  __syncthreads();
  if (lane == 0 && grp == 0) {
    out[row]         = shf[pair * 4] + shf[pair * 4 + 2];
    out[BATCH + row] = shf[pair * 4 + 1] + shf[pair * 4 + 3];
  }
}

// ---------------- launch ----------------
extern "C" void kernel_launch(void* const* d_in, const int* in_sizes, int n_in,
                              void* d_out, int out_size, void* d_ws, size_t ws_size,
                              hipStream_t stream) {
  (void)in_sizes; (void)n_in; (void)out_size; (void)ws_size;
  const float* state = (const float*)d_in[0];
  const float* W0 = (const float*)d_in[1];
  const float* b0 = (const float*)d_in[2];
  const float* W1 = (const float*)d_in[3];
  const float* b1 = (const float*)d_in[4];
  const float* W2 = (const float*)d_in[5];
  const float* b2 = (const float*)d_in[6];
  const int* idxR = (const int*)d_in[7];
  const int* lenR = (const int*)d_in[8];
  const int* idxS = (const int*)d_in[9];
  const int* lenS = (const int*)d_in[10];
  float* out = (float*)d_out;

  char* ws = (char*)d_ws;
  size_t off = 0;
  auto alloc = [&](size_t bytes) -> char* {
    char* p = ws + off;
    off = (off + bytes + 255) & ~(size_t)255;
    return p;
  };
  u16* As   = (u16*)alloc((size_t)BATCH * KP0 * 2);   // 17.8 MB
  u16* W0t  = (u16*)alloc((size_t)HID * KP0 * 2);     //  2.2 MB
  u16* W1t  = (u16*)alloc((size_t)HID * HID * 2);     //  2.1 MB
  u16* W2t  = (u16*)alloc((size_t)HID * LGN * 2);     //  2.1 MB
  u16* W2c  = (u16*)alloc((size_t)2 * 1024 * 2);      //  4 KB
  u16* h1   = (u16*)alloc((size_t)BATCH * HID * 2);   // 16.8 MB
  u16* h2   = (u16*)alloc((size_t)BATCH * HID * 2);   // 16.8 MB
  u16* lgts = (u16*)alloc((size_t)BATCH * LGN * 2);   // 16.8 MB

  k_cvt<<<7489, 512, 0, stream>>>(state, W0, W1, W2, As, W0t, W1t, W2t, W2c);

  gemm_bt<true,  KP0><<<512, 256, 0, stream>>>(As, W0t, b0, h1,   HID);
  gemm_bt<true,  HID><<<512, 256, 0, stream>>>(h1, W1t, b1, h2,   HID);
  gemm_bt<false, HID><<<512, 256, 0, stream>>>(h2, W2t, b2, lgts, LGN);

  k_sample<<<2048, 512, 0, stream>>>(lgts, h2, W2c, b2, idxR, lenR, idxS, lenS, out);
}